// Round 8
// baseline (307.043 us; speedup 1.0000x reference)
//
#include <hip/hip_runtime.h>

#define SEQ    512
#define NH     16
#define DH     64
#define DMODEL 1024
#define NB     16
#define MROWS  (NB*SEQ)      // 8192
#define MAXL   512

typedef _Float16 f16;
typedef f16  f16x8 __attribute__((ext_vector_type(8)));
typedef f16  f16x4 __attribute__((ext_vector_type(4)));
typedef float f32x4 __attribute__((ext_vector_type(4)));

// async global->LDS, 16B/lane; global addr per-lane, LDS dest = wave-uniform base + lane*16
__device__ static inline void gll16(const f16* g, f16* l) {
    __builtin_amdgcn_global_load_lds(
        (const __attribute__((address_space(1))) void*)(g),
        (__attribute__((address_space(3))) void*)(l), 16, 0, 0);
}

// ---------------------------------------------------------------------------
// fused prep:
//  blocks 0..1023     : x -> f16 (grid-strided, 8 float4/thread)
//  blocks 1024..4095  : wqkv -> f16 transposed
//  blocks 4096..5119  : wout -> f16 transposed
//  blocks 5120..5135  : rel2[h][i] = rel[i][h] * log2(e)  (per-head bias table)
// ---------------------------------------------------------------------------
__global__ __launch_bounds__(256)
void prep(const float* __restrict__ x, f16* __restrict__ xh,
          const float* __restrict__ wqkv, f16* __restrict__ wqkvT,
          const float* __restrict__ wout, f16* __restrict__ woutT,
          const float* __restrict__ rel, float* __restrict__ rel2)
{
    const int bid = blockIdx.x, t = threadIdx.x;
    if (bid < 1024) {
        const int S = 1024 * 256 * 4;
        int i0 = (bid * 256 + t) * 4;
        #pragma unroll
        for (int k = 0; k < 8; ++k) {
            int i = i0 + k * S;
            float4 v = *(const float4*)(x + i);
            f16x4 hh = { (f16)v.x, (f16)v.y, (f16)v.z, (f16)v.w };
            *(f16x4*)(xh + i) = hh;
        }
        return;
    }
    if (bid >= 5120) {
        int h = bid - 5120;
        for (int i = t; i < 2 * MAXL - 1; i += 256)
            rel2[h * 1024 + i] = rel[i * NH + h] * 1.44269504f;
        return;
    }
    __shared__ float tile[32][33];
    const float* in; f16* out; int C, gx, gy;
    if (bid < 4096) {
        int b2 = bid - 1024; in = wqkv; out = wqkvT; C = 3072;
        gx = b2 % 96; gy = b2 / 96;
    } else {
        int b2 = bid - 4096; in = wout; out = woutT; C = 1024;
        gx = b2 & 31; gy = b2 >> 5;
    }
    const int R = 1024;
    int tx = t & 31, ty = t >> 5;
    int c0 = gx * 32, r0 = gy * 32;
    #pragma unroll
    for (int i = 0; i < 4; ++i)
        tile[ty + i * 8][tx] = in[(size_t)(r0 + ty + i * 8) * C + c0 + tx];
    __syncthreads();
    #pragma unroll
    for (int i = 0; i < 4; ++i)
        out[(size_t)(c0 + ty + i * 8) * R + r0 + tx] = (f16)tile[tx][ty + i * 8];
}

// ---------------------------------------------------------------------------
// MFMA GEMM (R5-proven, unchanged): C(M x N) = A(M x K) @ Bt(N x K)^T + bias
// 128x128 tile, BK=64, 256 threads, 16x16x32 f16, fp32 acc.
// ---------------------------------------------------------------------------
template<int MODE>
__global__ __launch_bounds__(256)
void gemm_mfma(const f16* __restrict__ A, const f16* __restrict__ Bt,
               const float* __restrict__ bias, int N, int K,
               float* __restrict__ Cout,
               f16* __restrict__ qb, f16* __restrict__ kb, f16* __restrict__ vb)
{
    __shared__ f16 As[128 * 64];
    __shared__ f16 Bs[128 * 64];
    const int t = threadIdx.x;
    const int lane = t & 63, w = t >> 6;
    const int quad = lane >> 4, l16 = lane & 15;
    const int xr = l16 & 7;
    const int m0 = blockIdx.y * 128, n0 = blockIdx.x * 128;
    const int wm = (w & 1) * 64, wn = (w >> 1) * 64;

    f32x4 acc[4][4];
    #pragma unroll
    for (int i = 0; i < 4; ++i)
        #pragma unroll
        for (int j = 0; j < 4; ++j)
            acc[i][j] = f32x4{0.f, 0.f, 0.f, 0.f};

    const int sr8 = lane >> 3;
    const int sc8 = (lane & 7) ^ sr8;
    const f16* agp = A  + (size_t)(m0 + w * 32 + sr8) * K + sc8 * 8;
    const f16* bgp = Bt + (size_t)(n0 + w * 32 + sr8) * K + sc8 * 8;
    f16* asl = As + w * 2048;
    f16* bsl = Bs + w * 2048;

    for (int k0 = 0; k0 < K; k0 += 64) {
        __syncthreads();
        #pragma unroll
        for (int c = 0; c < 4; ++c) {
            gll16(agp + k0 + c * 8 * K, asl + c * 512);
            gll16(bgp + k0 + c * 8 * K, bsl + c * 512);
        }
        __syncthreads();
        #pragma unroll
        for (int ks = 0; ks < 2; ++ks) {
            f16x8 af[4], bf[4];
            #pragma unroll
            for (int ms = 0; ms < 4; ++ms)
                af[ms] = *(const f16x8*)&As[(wm + ms * 16 + l16) * 64
                                            + (((ks * 4 + quad) ^ xr) * 8)];
            #pragma unroll
            for (int ns = 0; ns < 4; ++ns)
                bf[ns] = *(const f16x8*)&Bs[(wn + ns * 16 + l16) * 64
                                            + (((ks * 4 + quad) ^ xr) * 8)];
            #pragma unroll
            for (int ms = 0; ms < 4; ++ms)
                #pragma unroll
                for (int ns = 0; ns < 4; ++ns)
                    acc[ms][ns] = __builtin_amdgcn_mfma_f32_16x16x32_f16(
                        af[ms], bf[ns], acc[ms][ns], 0, 0, 0);
        }
    }

    if (MODE == 0) {
        #pragma unroll
        for (int ns = 0; ns < 4; ++ns) {
            int col = n0 + wn + ns * 16 + l16;
            float bv = bias[col];
            int which = col >> 10;
            int hh = (col & 1023) >> 6, d = col & 63;
            #pragma unroll
            for (int ms = 0; ms < 4; ++ms) {
                int rowb = m0 + wm + ms * 16 + quad * 4;
                int bb_ = rowb >> 9, n_ = rowb & 511;
                if (which == 0) {
                    #pragma unroll
                    for (int reg = 0; reg < 4; ++reg)
                        qb[((size_t)(bb_ * NH + hh) * SEQ + n_ + reg) * DH + d] =
                            (f16)(acc[ms][ns][reg] + bv);
                } else if (which == 2) {
                    f16x4 pk;
                    #pragma unroll
                    for (int reg = 0; reg < 4; ++reg)
                        pk[reg] = (f16)(acc[ms][ns][reg] + bv);
                    int c8s = ((n_ >> 3) & 7) ^ (d & 7);
                    *(f16x4*)(vb + ((size_t)(bb_ * NH + hh) * DH + d) * SEQ
                                 + (n_ & ~63) + c8s * 8 + (n_ & 7)) = pk;
                } else {
                    #pragma unroll
                    for (int reg = 0; reg < 4; ++reg) {
                        int n = n_ + reg;
                        int dd = (((d >> 3) ^ (n & 7)) * 8) + (d & 7);
                        kb[((size_t)(bb_ * NH + hh) * SEQ + n) * DH + dd] =
                            (f16)(acc[ms][ns][reg] + bv);
                    }
                }
            }
        }
    } else {
        #pragma unroll
        for (int ns = 0; ns < 4; ++ns) {
            int col = n0 + wn + ns * 16 + l16;
            float bv = bias[col];
            #pragma unroll
            for (int ms = 0; ms < 4; ++ms) {
                int rowb = m0 + wm + ms * 16 + quad * 4;
                #pragma unroll
                for (int reg = 0; reg < 4; ++reg)
                    Cout[(size_t)(rowb + reg) * N + col] = acc[ms][ns][reg] + bv;
            }
        }
    }
}

// ---------------------------------------------------------------------------
// MFMA attention (R5 8-wave shape + fragment-read sharing + global rel bias).
// Block = (b,h), 512 threads = 8 waves; wave owns 64 q-rows (4 chunks of 16).
// Per 128-key tile: QK processes q-chunk PAIRS so each K-fragment b128 read
// feeds 2 chunks; PV shares each V-fragment across the pair. Bias read from
// global rel2[h][1024] (L1-resident) instead of LDS. LDS reads/kt/wave:
// 32 K-frag + 32 V-frag + 16 P b128 + 32 P-write b64 (~half of R5).
// Transposed-S, no online rescale (|s| << f16 overflow), per-lane row-sum.
// ---------------------------------------------------------------------------
__global__ __launch_bounds__(512, 2)
void attn_mfma(const f16* __restrict__ qb, const f16* __restrict__ kb,
               const f16* __restrict__ vb, const float* __restrict__ rel2,
               f16* __restrict__ ob)
{
    __shared__ f16 Ks[128 * 64];         // [key][d-chunk8 ^ (key&7)]       16 KB
    __shared__ f16 Vt[64 * 128];         // [d][key; chunk8 ^ (d&7) per 64] 16 KB
    __shared__ f16 Pw[8][2][16 * 64];    // [wave][cc][q][key64 ^ (q&7)]    32 KB

    const int t = threadIdx.x;
    const int lane = t & 63, w = t >> 6;
    const int quad = lane >> 4, l16 = lane & 15;
    const int xr = l16 & 7;
    const int bh = blockIdx.x;
    const int h = bh & 15, b = bh >> 4;
    const float* r2 = rel2 + h * 1024;

    // Q B-fragments: chunk c -> Q[q=w*64+c*16+l16][d=quad*8+j (+32)]
    f16x8 qf[4][2];
    #pragma unroll
    for (int c = 0; c < 4; ++c) {
        const f16* qrow = qb + ((size_t)bh * SEQ + w * 64 + c * 16 + l16) * DH + quad * 8;
        qf[c][0] = *(const f16x8*)(qrow);
        qf[c][1] = *(const f16x8*)(qrow + 32);
    }

    f32x4 o[4][4];
    float lsum[4];
    #pragma unroll
    for (int c = 0; c < 4; ++c) {
        lsum[c] = 0.f;
        #pragma unroll
        for (int dt = 0; dt < 4; ++dt) o[c][dt] = f32x4{0.f, 0.f, 0.f, 0.f};
    }

    const f16* kbase = kb + (size_t)bh * SEQ * DH;
    const f16* vbase = vb + (size_t)bh * DH * SEQ;

    for (int kt = 0; kt < 4; ++kt) {
        __syncthreads();
        // stage K tile (128 keys x 64 d) and V^T tile (64 d x 128 keys)
        #pragma unroll
        for (int r = 0; r < 2; ++r) {
            const f16* src = kbase + (size_t)(kt * 128 + r * 64 + w * 8 + (lane >> 3)) * DH
                           + (lane & 7) * 8;
            gll16(src, Ks + r * 4096 + w * 512);
        }
        #pragma unroll
        for (int r = 0; r < 2; ++r) {
            const f16* src = vbase + (size_t)(r * 32 + w * 4 + (lane >> 4)) * SEQ
                           + kt * 128 + ((lane >> 3) & 1) * 64 + (lane & 7) * 8;
            gll16(src, Vt + r * 4096 + w * 512);
        }
        __syncthreads();

        #pragma unroll
        for (int cp = 0; cp < 2; ++cp) {
            // ---- S^T for q-chunk pair: one K-frag read feeds both chunks ----
            f32x4 sT[2][8];
            #pragma unroll
            for (int mt = 0; mt < 8; ++mt) {
                const f16* kr = &Ks[(mt * 16 + l16) * 64];
                f16x8 a0 = *(const f16x8*)(kr + ((quad ^ xr) * 8));
                f16x8 a1 = *(const f16x8*)(kr + (((4 + quad) ^ xr) * 8));
                #pragma unroll
                for (int cc = 0; cc < 2; ++cc) {
                    f32x4 s = f32x4{0.f, 0.f, 0.f, 0.f};
                    s = __builtin_amdgcn_mfma_f32_16x16x32_f16(a0, qf[cp * 2 + cc][0], s, 0, 0, 0);
                    s = __builtin_amdgcn_mfma_f32_16x16x32_f16(a1, qf[cp * 2 + cc][1], s, 0, 0, 0);
                    sT[cc][mt] = s;
                }
            }

            // ---- per 64-key half: exp + P-write (both chunks), then PV ----
            #pragma unroll
            for (int g = 0; g < 2; ++g) {
                #pragma unroll
                for (int cc = 0; cc < 2; ++cc) {
                    const int c = cp * 2 + cc;
                    const int cb0 = w * 64 + c * 16 + l16 + (MAXL - 1) - kt * 128 - quad * 4;
                    f16* pw = &Pw[w][cc][0];
                    #pragma unroll
                    for (int m4 = 0; m4 < 4; ++m4) {
                        int mt = g * 4 + m4;
                        f16x4 pk;
                        #pragma unroll
                        for (int reg = 0; reg < 4; ++reg) {
                            float e = exp2f(fmaf(sT[cc][mt][reg], 0.180336878f,
                                                 r2[cb0 - mt * 16 - reg]));
                            lsum[c] += e;
                            pk[reg] = (f16)e;
                        }
                        int c8 = (m4 * 2 + (quad >> 1)) ^ xr;
                        *(f16x4*)&pw[l16 * 64 + c8 * 8 + (quad & 1) * 4] = pk;
                    }
                }
                __builtin_amdgcn_s_waitcnt(0xC07F);   // lgkmcnt(0): P visible in-wave

                #pragma unroll
                for (int s2 = 0; s2 < 2; ++s2) {
                    f16x8 vf[4];
                    #pragma unroll
                    for (int dt = 0; dt < 4; ++dt)
                        vf[dt] = *(const f16x8*)&Vt[(dt * 16 + l16) * 128 + g * 64
                                                    + (((s2 * 4 + quad) ^ xr) * 8)];
                    #pragma unroll
                    for (int cc = 0; cc < 2; ++cc) {
                        const int c = cp * 2 + cc;
                        f16x8 pa = *(const f16x8*)&Pw[w][cc][l16 * 64
                                                    + (((s2 * 4 + quad) ^ xr) * 8)];
                        #pragma unroll
                        for (int dt = 0; dt < 4; ++dt)
                            o[c][dt] = __builtin_amdgcn_mfma_f32_16x16x32_f16(
                                pa, vf[dt], o[c][dt], 0, 0, 0);
                    }
                }
            }
        }
    }

    // ---- finalize: quad-reduce row-sums, normalize, write f16 [b][n][h*dh] ----
    #pragma unroll
    for (int c = 0; c < 4; ++c) {
        float ls = lsum[c];
        ls += __shfl_xor(ls, 16, 64);
        ls += __shfl_xor(ls, 32, 64);
        #pragma unroll
        for (int reg = 0; reg < 4; ++reg) {
            float inv = 1.0f / __shfl(ls, quad * 4 + reg, 64);
            size_t rbase = ((size_t)b * SEQ + w * 64 + c * 16 + quad * 4 + reg) * DMODEL
                         + h * DH;
            #pragma unroll
            for (int dt = 0; dt < 4; ++dt)
                ob[rbase + dt * 16 + l16] = (f16)(o[c][dt][reg] * inv);
        }
    }
}

// ---------------------------------------------------------------------------
extern "C" void kernel_launch(void* const* d_in, const int* in_sizes, int n_in,
                              void* d_out, int out_size, void* d_ws, size_t ws_size,
                              hipStream_t stream)
{
    const float* x    = (const float*)d_in[0];
    const float* wqkv = (const float*)d_in[1];
    const float* bqkv = (const float*)d_in[2];
    const float* rel  = (const float*)d_in[3];
    const float* wout = (const float*)d_in[4];
    const float* bout = (const float*)d_in[5];
    float* out = (float*)d_out;
    char* ws = (char*)d_ws;

    const size_t XH = (size_t)MROWS * DMODEL;            // 8M elements
    f16* xh    = (f16*)(ws);
    f16* wqkvT = (f16*)(ws + 2 * XH);
    f16* woutT = wqkvT + (size_t)3 * DMODEL * DMODEL;
    f16* qbuf  = woutT + (size_t)DMODEL * DMODEL;
    f16* kbuf  = qbuf + XH;
    f16* vbuf  = kbuf + XH;
    f16* abuf  = vbuf + XH;
    float* rel2 = (float*)(abuf + XH);                   // 16 x 1024 f32

    prep<<<5136, 256, 0, stream>>>(x, xh, wqkv, wqkvT, wout, woutT, rel, rel2);

    gemm_mfma<0><<<dim3(3 * DMODEL / 128, MROWS / 128), 256, 0, stream>>>(
        xh, wqkvT, bqkv, 3 * DMODEL, DMODEL, nullptr, qbuf, kbuf, vbuf);

    attn_mfma<<<NB * NH, 512, 0, stream>>>(qbuf, kbuf, vbuf, rel2, abuf);

    gemm_mfma<1><<<dim3(DMODEL / 128, MROWS / 128), 256, 0, stream>>>(
        abuf, woutT, bout, DMODEL, DMODEL, out, nullptr, nullptr, nullptr);
}